// Round 1
// baseline (1535.146 us; speedup 1.0000x reference)
//
#include <hip/hip_runtime.h>
#include <math.h>

// ---------- helpers ----------

__device__ inline unsigned fenc(float f) {
    unsigned u = __float_as_uint(f);
    return (u & 0x80000000u) ? ~u : (u | 0x80000000u);
}
__device__ inline float fdec(unsigned u) {
    return __uint_as_float((u & 0x80000000u) ? (u ^ 0x80000000u) : ~u);
}

__device__ inline float wave_reduce_sum(float v) {
    #pragma unroll
    for (int off = 32; off > 0; off >>= 1) v += __shfl_down(v, off, 64);
    return v;
}

__device__ inline float lrelu(float x) { return x > 0.f ? x : 0.2f * x; }

// ---------- GEMM 1: h1[N,256] = x[N,128] @ W1[128,256] ----------
__global__ __launch_bounds__(256) void gemm1_kernel(const float* __restrict__ x,
                                                    const float* __restrict__ W,
                                                    float* __restrict__ h, int N) {
    __shared__ float xs[16 * 128];
    int base = blockIdx.x * 16;
    int tid = threadIdx.x;
    for (int i = tid; i < 16 * 128; i += 256) {
        int n = base + (i >> 7);
        xs[i] = (n < N) ? x[base * 128 + i] : 0.f;
    }
    __syncthreads();
    float acc[16];
    #pragma unroll
    for (int j = 0; j < 16; j++) acc[j] = 0.f;
    for (int k = 0; k < 128; k++) {
        float wk = W[k * 256 + tid];
        #pragma unroll
        for (int j = 0; j < 16; j++) acc[j] += xs[j * 128 + k] * wk;
    }
    #pragma unroll
    for (int j = 0; j < 16; j++) {
        int n = base + j;
        if (n < N) h[n * 256 + tid] = acc[j];
    }
}

// ---------- GEMM 2: h2[N,64] = x2[N,256] @ W2[256,64] ----------
__global__ __launch_bounds__(256) void gemm2_kernel(const float* __restrict__ x2,
                                                    const float* __restrict__ W,
                                                    float* __restrict__ h2, int N) {
    __shared__ float xs[16 * 256];
    int base = blockIdx.x * 16;
    int tid = threadIdx.x;
    for (int i = tid; i < 16 * 256; i += 256) {
        int n = base + (i >> 8);
        xs[i] = (n < N) ? x2[base * 256 + i] : 0.f;
    }
    __syncthreads();
    int c = tid & 63, sub = tid >> 6;
    float acc[4] = {0.f, 0.f, 0.f, 0.f};
    for (int k = 0; k < 256; k++) {
        float wk = W[k * 64 + c];
        #pragma unroll
        for (int j = 0; j < 4; j++) acc[j] += xs[(sub + 4 * j) * 256 + k] * wk;
    }
    #pragma unroll
    for (int j = 0; j < 4; j++) {
        int n = base + sub + 4 * j;
        if (n < N) h2[n * 64 + c] = acc[j];
    }
}

// ---------- scores layer 1: s[n,h] = sum_d h1[n,h,d]*a[h,d] ----------
__global__ __launch_bounds__(256) void scores1_kernel(const float* __restrict__ h1,
                                                      const float* __restrict__ a_src,
                                                      const float* __restrict__ a_dst,
                                                      float* __restrict__ s_src,
                                                      float* __restrict__ s_dst, int N) {
    int n = blockIdx.x;
    if (n >= N) return;
    int t = threadIdx.x;
    float hv = h1[n * 256 + t];
    float ps = wave_reduce_sum(hv * a_src[t]);
    float pd = wave_reduce_sum(hv * a_dst[t]);
    int lane = t & 63, head = t >> 6;
    if (lane == 0) {
        s_src[n * 4 + head] = ps;
        s_dst[n * 4 + head] = pd;
    }
}

// ---------- scores layer 2 ----------
__global__ __launch_bounds__(256) void scores2_kernel(const float* __restrict__ h2,
                                                      const float* __restrict__ a_src,
                                                      const float* __restrict__ a_dst,
                                                      float* __restrict__ s_src,
                                                      float* __restrict__ s_dst, int N) {
    int lane = threadIdx.x & 63, sub = threadIdx.x >> 6;
    int n = blockIdx.x * 4 + sub;
    if (n >= N) return;
    float hv = h2[n * 64 + lane];
    float ps = wave_reduce_sum(hv * a_src[lane]);
    float pd = wave_reduce_sum(hv * a_dst[lane]);
    if (lane == 0) { s_src[n] = ps; s_dst[n] = pd; }
}

// ---------- edge max, layer 1 (4 heads) ----------
__global__ __launch_bounds__(256) void edgemax1_kernel(const int* __restrict__ ei,
                                                       const float* __restrict__ ssrc,
                                                       const float* __restrict__ sdst,
                                                       unsigned* __restrict__ m1,
                                                       int E, int Etot) {
    int i = blockIdx.x * 256 + threadIdx.x;
    if (i >= Etot) return;
    int s, d;
    if (i < E) { s = ei[i]; d = ei[E + i]; } else { s = d = i - E; }
    #pragma unroll
    for (int h = 0; h < 4; h++) {
        float e = lrelu(ssrc[s * 4 + h] + sdst[d * 4 + h]);
        atomicMax(&m1[d * 4 + h], fenc(e));
    }
}

// ---------- edge aggregate, layer 1: one wave per edge, lane = dim ----------
__global__ __launch_bounds__(256) void edgeagg1_kernel(const int* __restrict__ ei,
                                                       const float* __restrict__ ssrc,
                                                       const float* __restrict__ sdst,
                                                       const unsigned* __restrict__ m1,
                                                       const float* __restrict__ h1,
                                                       float* __restrict__ acc1,
                                                       float* __restrict__ denom1,
                                                       int E, int Etot) {
    long long t = (long long)blockIdx.x * 256 + threadIdx.x;
    int edge = (int)(t >> 6);
    int lane = (int)(t & 63);
    if (edge >= Etot) return;
    int s, d;
    if (edge < E) { s = ei[edge]; d = ei[E + edge]; } else { s = d = edge - E; }
    float w[4];
    #pragma unroll
    for (int h = 0; h < 4; h++) {
        float e = lrelu(ssrc[s * 4 + h] + sdst[d * 4 + h]);
        w[h] = expf(e - fdec(m1[d * 4 + h]));
    }
    #pragma unroll
    for (int h = 0; h < 4; h++) {
        float hv = h1[s * 256 + h * 64 + lane];
        atomicAdd(&acc1[d * 256 + h * 64 + lane], w[h] * hv);
    }
    if (lane == 0) {
        #pragma unroll
        for (int h = 0; h < 4; h++) atomicAdd(&denom1[d * 4 + h], w[h]);
    }
}

// ---------- normalize + bias + ELU (in place: acc1 -> x2) ----------
__global__ __launch_bounds__(256) void norm1_kernel(float* __restrict__ acc1,
                                                    const float* __restrict__ denom1,
                                                    const float* __restrict__ b1, int N) {
    int t = blockIdx.x * 256 + threadIdx.x;
    if (t >= N * 256) return;
    int n = t >> 8;
    int c = t & 255;
    int h = c >> 6;
    float v = acc1[t] / denom1[n * 4 + h] + b1[c];
    acc1[t] = v > 0.f ? v : expf(v) - 1.f;
}

// ---------- edge max, layer 2 (1 head) ----------
__global__ __launch_bounds__(256) void edgemax2_kernel(const int* __restrict__ ei,
                                                       const float* __restrict__ ssrc,
                                                       const float* __restrict__ sdst,
                                                       unsigned* __restrict__ m2,
                                                       int E, int Etot) {
    int i = blockIdx.x * 256 + threadIdx.x;
    if (i >= Etot) return;
    int s, d;
    if (i < E) { s = ei[i]; d = ei[E + i]; } else { s = d = i - E; }
    float e = lrelu(ssrc[s] + sdst[d]);
    atomicMax(&m2[d], fenc(e));
}

// ---------- edge aggregate, layer 2 ----------
__global__ __launch_bounds__(256) void edgeagg2_kernel(const int* __restrict__ ei,
                                                       const float* __restrict__ ssrc,
                                                       const float* __restrict__ sdst,
                                                       const unsigned* __restrict__ m2,
                                                       const float* __restrict__ h2,
                                                       float* __restrict__ acc2,
                                                       float* __restrict__ denom2,
                                                       int E, int Etot) {
    long long t = (long long)blockIdx.x * 256 + threadIdx.x;
    int edge = (int)(t >> 6);
    int lane = (int)(t & 63);
    if (edge >= Etot) return;
    int s, d;
    if (edge < E) { s = ei[edge]; d = ei[E + edge]; } else { s = d = edge - E; }
    float e = lrelu(ssrc[s] + sdst[d]);
    float w = expf(e - fdec(m2[d]));
    atomicAdd(&acc2[d * 64 + lane], w * h2[s * 64 + lane]);
    if (lane == 0) atomicAdd(&denom2[d], w);
}

// ---------- final min over nodes ----------
__global__ __launch_bounds__(256) void final_min_kernel(const float* __restrict__ acc2,
                                                        const float* __restrict__ denom2,
                                                        const float* __restrict__ b2,
                                                        unsigned* __restrict__ minenc, int N) {
    int d = threadIdx.x & 63, r = threadIdx.x >> 6;
    float bd = b2[d];
    float lm = INFINITY;
    for (int n = blockIdx.x * 4 + r; n < N; n += gridDim.x * 4) {
        float v = acc2[n * 64 + d] / denom2[n] + bd;
        lm = fminf(lm, v);
    }
    __shared__ float sm[256];
    sm[threadIdx.x] = lm;
    __syncthreads();
    if (r == 0) {
        lm = fminf(fminf(sm[d], sm[64 + d]), fminf(sm[128 + d], sm[192 + d]));
        atomicMin(&minenc[d], fenc(lm));
    }
}

__global__ void decode_kernel(const unsigned* __restrict__ minenc, float* __restrict__ out) {
    int d = threadIdx.x;
    if (d < 64) out[d] = fdec(minenc[d]);
}

// ---------- launch ----------
extern "C" void kernel_launch(void* const* d_in, const int* in_sizes, int n_in,
                              void* d_out, int out_size, void* d_ws, size_t ws_size,
                              hipStream_t stream) {
    const float* x      = (const float*)d_in[0];
    const int*   ei     = (const int*)d_in[1];
    const float* W1     = (const float*)d_in[2];
    const float* a_src1 = (const float*)d_in[3];
    const float* a_dst1 = (const float*)d_in[4];
    const float* b1     = (const float*)d_in[5];
    const float* W2     = (const float*)d_in[6];
    const float* a_src2 = (const float*)d_in[7];
    const float* a_dst2 = (const float*)d_in[8];
    const float* b2     = (const float*)d_in[9];
    float* out = (float*)d_out;

    const int N = in_sizes[0] / 128;
    const int E = in_sizes[1] / 2;
    const int Etot = E + N;

    // workspace layout (floats)
    float* ws = (float*)d_ws;
    float* h1     = ws;                       // N*256
    float* acc1   = h1 + (size_t)N * 256;     // N*256 (becomes x2 after norm1)
    float* h2     = acc1 + (size_t)N * 256;   // N*64
    float* acc2   = h2 + (size_t)N * 64;      // N*64
    float* ssrc1  = acc2 + (size_t)N * 64;    // 4N
    float* sdst1  = ssrc1 + (size_t)N * 4;    // 4N
    unsigned* m1  = (unsigned*)(sdst1 + (size_t)N * 4);  // 4N
    float* denom1 = (float*)m1 + (size_t)N * 4;          // 4N
    float* ssrc2  = denom1 + (size_t)N * 4;   // N
    float* sdst2  = ssrc2 + N;                // N
    unsigned* m2  = (unsigned*)(sdst2 + N);   // N
    float* denom2 = (float*)m2 + N;           // N
    unsigned* minenc = (unsigned*)(denom2 + N); // 64

    // zero-init accumulators; m uses encoded-float where 0 < any finite enc
    hipMemsetAsync(acc1, 0, (size_t)N * 256 * 4, stream);
    hipMemsetAsync(acc2, 0, (size_t)N * 64 * 4, stream);
    hipMemsetAsync(m1, 0, (size_t)N * 8 * 4, stream);   // m1 + denom1 contiguous
    hipMemsetAsync(m2, 0, (size_t)N * 2 * 4, stream);   // m2 + denom2 contiguous
    hipMemsetAsync(minenc, 0xFF, 64 * 4, stream);

    int nb16 = (N + 15) / 16;
    gemm1_kernel<<<nb16, 256, 0, stream>>>(x, W1, h1, N);
    scores1_kernel<<<N, 256, 0, stream>>>(h1, a_src1, a_dst1, ssrc1, sdst1, N);
    edgemax1_kernel<<<(Etot + 255) / 256, 256, 0, stream>>>(ei, ssrc1, sdst1, m1, E, Etot);
    {
        long long tt = (long long)Etot * 64;
        int blocks = (int)((tt + 255) / 256);
        edgeagg1_kernel<<<blocks, 256, 0, stream>>>(ei, ssrc1, sdst1, m1, h1, acc1, denom1, E, Etot);
    }
    norm1_kernel<<<(N * 256 + 255) / 256, 256, 0, stream>>>(acc1, denom1, b1, N);
    gemm2_kernel<<<nb16, 256, 0, stream>>>(acc1, W2, h2, N);
    scores2_kernel<<<(N + 3) / 4, 256, 0, stream>>>(h2, a_src2, a_dst2, ssrc2, sdst2, N);
    edgemax2_kernel<<<(Etot + 255) / 256, 256, 0, stream>>>(ei, ssrc2, sdst2, m2, E, Etot);
    {
        long long tt = (long long)Etot * 64;
        int blocks = (int)((tt + 255) / 256);
        edgeagg2_kernel<<<blocks, 256, 0, stream>>>(ei, ssrc2, sdst2, m2, h2, acc2, denom2, E, Etot);
    }
    final_min_kernel<<<512, 256, 0, stream>>>(acc2, denom2, b2, minenc, N);
    decode_kernel<<<1, 64, 0, stream>>>(minenc, out);
}

// Round 2
// 649.387 us; speedup vs baseline: 2.3640x; 2.3640x over previous
//
#include <hip/hip_runtime.h>
#include <math.h>

// ---------- helpers ----------

__device__ inline unsigned fenc(float f) {
    unsigned u = __float_as_uint(f);
    return (u & 0x80000000u) ? ~u : (u | 0x80000000u);
}
__device__ inline float fdec(unsigned u) {
    return __uint_as_float((u & 0x80000000u) ? (u ^ 0x80000000u) : ~u);
}

__device__ inline float wave_reduce_sum(float v) {
    #pragma unroll
    for (int off = 32; off > 0; off >>= 1) v += __shfl_down(v, off, 64);
    return v;
}

// ---------- GEMM 1: h1[N,256] = x[N,128] @ W1[128,256] ----------
__global__ __launch_bounds__(256) void gemm1_kernel(const float* __restrict__ x,
                                                    const float* __restrict__ W,
                                                    float* __restrict__ h, int N) {
    __shared__ float xs[16 * 128];
    int base = blockIdx.x * 16;
    int tid = threadIdx.x;
    for (int i = tid; i < 16 * 128; i += 256) {
        int n = base + (i >> 7);
        xs[i] = (n < N) ? x[base * 128 + i] : 0.f;
    }
    __syncthreads();
    float acc[16];
    #pragma unroll
    for (int j = 0; j < 16; j++) acc[j] = 0.f;
    for (int k = 0; k < 128; k++) {
        float wk = W[k * 256 + tid];
        #pragma unroll
        for (int j = 0; j < 16; j++) acc[j] += xs[j * 128 + k] * wk;
    }
    #pragma unroll
    for (int j = 0; j < 16; j++) {
        int n = base + j;
        if (n < N) h[n * 256 + tid] = acc[j];
    }
}

// ---------- GEMM 2: h2[N,64] = x2[N,256] @ W2[256,64] ----------
__global__ __launch_bounds__(256) void gemm2_kernel(const float* __restrict__ x2,
                                                    const float* __restrict__ W,
                                                    float* __restrict__ h2, int N) {
    __shared__ float xs[16 * 256];
    int base = blockIdx.x * 16;
    int tid = threadIdx.x;
    for (int i = tid; i < 16 * 256; i += 256) {
        int n = base + (i >> 8);
        xs[i] = (n < N) ? x2[base * 256 + i] : 0.f;
    }
    __syncthreads();
    int c = tid & 63, sub = tid >> 6;
    float acc[4] = {0.f, 0.f, 0.f, 0.f};
    for (int k = 0; k < 256; k++) {
        float wk = W[k * 64 + c];
        #pragma unroll
        for (int j = 0; j < 4; j++) acc[j] += xs[(sub + 4 * j) * 256 + k] * wk;
    }
    #pragma unroll
    for (int j = 0; j < 4; j++) {
        int n = base + sub + 4 * j;
        if (n < N) h2[n * 64 + c] = acc[j];
    }
}

// ---------- scores layer 1: s[n,h] = sum_d h1[n,h,d]*a[h,d] ----------
__global__ __launch_bounds__(256) void scores1_kernel(const float* __restrict__ h1,
                                                      const float* __restrict__ a_src,
                                                      const float* __restrict__ a_dst,
                                                      float* __restrict__ s_src,
                                                      float* __restrict__ s_dst, int N) {
    int n = blockIdx.x;
    if (n >= N) return;
    int t = threadIdx.x;
    float hv = h1[n * 256 + t];
    float ps = wave_reduce_sum(hv * a_src[t]);
    float pd = wave_reduce_sum(hv * a_dst[t]);
    int lane = t & 63, head = t >> 6;
    if (lane == 0) {
        s_src[n * 4 + head] = ps;
        s_dst[n * 4 + head] = pd;
    }
}

// ---------- scores layer 2 ----------
__global__ __launch_bounds__(256) void scores2_kernel(const float* __restrict__ h2,
                                                      const float* __restrict__ a_src,
                                                      const float* __restrict__ a_dst,
                                                      float* __restrict__ s_src,
                                                      float* __restrict__ s_dst, int N) {
    int lane = threadIdx.x & 63, sub = threadIdx.x >> 6;
    int n = blockIdx.x * 4 + sub;
    if (n >= N) return;
    float hv = h2[n * 64 + lane];
    float ps = wave_reduce_sum(hv * a_src[lane]);
    float pd = wave_reduce_sum(hv * a_dst[lane]);
    if (lane == 0) { s_src[n] = ps; s_dst[n] = pd; }
}

// ---------- CSR build: histogram over dst ----------
__global__ __launch_bounds__(256) void hist_kernel(const int* __restrict__ ei,
                                                   int* __restrict__ deg, int E, int Etot) {
    int i = blockIdx.x * 256 + threadIdx.x;
    if (i >= Etot) return;
    int d = (i < E) ? ei[E + i] : (i - E);
    atomicAdd(&deg[d], 1);
}

// ---------- per-chunk sums (chunk = 256 elems) ----------
__global__ __launch_bounds__(256) void chunksum_kernel(const int* __restrict__ deg,
                                                       int* __restrict__ csum, int M) {
    __shared__ int sm[256];
    int t = blockIdx.x * 256 + threadIdx.x;
    sm[threadIdx.x] = (t < M) ? deg[t] : 0;
    __syncthreads();
    for (int off = 128; off > 0; off >>= 1) {
        if (threadIdx.x < off) sm[threadIdx.x] += sm[threadIdx.x + off];
        __syncthreads();
    }
    if (threadIdx.x == 0) csum[blockIdx.x] = sm[0];
}

// ---------- exclusive scan of chunk sums (single block, nchunks <= 256) ----------
__global__ __launch_bounds__(256) void scanchunks_kernel(const int* __restrict__ csum,
                                                         int* __restrict__ coffset, int nchunks) {
    __shared__ int sm[256];
    int v = (threadIdx.x < nchunks) ? csum[threadIdx.x] : 0;
    sm[threadIdx.x] = v;
    __syncthreads();
    for (int off = 1; off < 256; off <<= 1) {
        int a = (threadIdx.x >= off) ? sm[threadIdx.x - off] : 0;
        __syncthreads();
        sm[threadIdx.x] += a;
        __syncthreads();
    }
    coffset[threadIdx.x] = sm[threadIdx.x] - v;   // exclusive
}

// ---------- per-chunk exclusive scan -> rowptr ----------
__global__ __launch_bounds__(256) void rowptr_kernel(const int* __restrict__ deg,
                                                     const int* __restrict__ coffset,
                                                     int* __restrict__ rowptr, int M) {
    __shared__ int sm[256];
    int t = blockIdx.x * 256 + threadIdx.x;
    int v = (t < M) ? deg[t] : 0;
    sm[threadIdx.x] = v;
    __syncthreads();
    for (int off = 1; off < 256; off <<= 1) {
        int a = (threadIdx.x >= off) ? sm[threadIdx.x - off] : 0;
        __syncthreads();
        sm[threadIdx.x] += a;
        __syncthreads();
    }
    if (t < M) rowptr[t] = coffset[blockIdx.x] + sm[threadIdx.x] - v;
}

// ---------- scatter src indices into dst-grouped order ----------
__global__ __launch_bounds__(256) void scatter_kernel(const int* __restrict__ ei,
                                                      int* __restrict__ cursor,
                                                      int* __restrict__ srcbuf, int E, int Etot) {
    int i = blockIdx.x * 256 + threadIdx.x;
    if (i >= Etot) return;
    int s, d;
    if (i < E) { s = ei[i]; d = ei[E + i]; } else { s = d = i - E; }
    int pos = atomicAdd(&cursor[d], 1);
    srcbuf[pos] = s;
}

// ---------- layer-1 aggregation: one wave per dst, online softmax, fused norm+bias+ELU ----------
__global__ __launch_bounds__(256) void agg1_kernel(const int* __restrict__ rowptr,
                                                   const int* __restrict__ srcbuf,
                                                   const float* __restrict__ ssrc,
                                                   const float* __restrict__ sdst,
                                                   const float* __restrict__ h1,
                                                   const float* __restrict__ b1,
                                                   float* __restrict__ x2, int N) {
    int lane = threadIdx.x & 63, w = threadIdx.x >> 6;
    int d = blockIdx.x * 4 + w;
    if (d >= N) return;
    int row = rowptr[d], end = rowptr[d + 1];
    float4 sd = *(const float4*)(sdst + d * 4);
    float m[4], l[4], acc[4];
    #pragma unroll
    for (int h = 0; h < 4; h++) { m[h] = -INFINITY; l[h] = 0.f; acc[h] = 0.f; }
    for (int base = row; base < end; base += 64) {
        int cnt = min(64, end - base);
        int sv = (lane < cnt) ? srcbuf[base + lane] : 0;
        for (int j = 0; j < cnt; j++) {
            int s = __shfl(sv, j, 64);
            float4 ss = *(const float4*)(ssrc + s * 4);
            const float* hp = h1 + (size_t)s * 256 + lane;
            float hv[4] = {hp[0], hp[64], hp[128], hp[192]};
            float ev[4] = {ss.x + sd.x, ss.y + sd.y, ss.z + sd.z, ss.w + sd.w};
            #pragma unroll
            for (int h = 0; h < 4; h++) {
                float e = ev[h];
                e = e > 0.f ? e : 0.2f * e;
                float nm = fmaxf(m[h], e);
                float sc = __expf(m[h] - nm);
                float wt = __expf(e - nm);
                acc[h] = acc[h] * sc + wt * hv[h];
                l[h] = l[h] * sc + wt;
                m[h] = nm;
            }
        }
    }
    #pragma unroll
    for (int h = 0; h < 4; h++) {
        float v = acc[h] / l[h] + b1[h * 64 + lane];
        v = v > 0.f ? v : __expf(v) - 1.f;      // ELU
        x2[(size_t)d * 256 + h * 64 + lane] = v;
    }
}

// ---------- layer-2 aggregation + fused global min ----------
__global__ __launch_bounds__(256) void agg2_kernel(const int* __restrict__ rowptr,
                                                   const int* __restrict__ srcbuf,
                                                   const float* __restrict__ ssrc,
                                                   const float* __restrict__ sdst,
                                                   const float* __restrict__ h2,
                                                   const float* __restrict__ b2,
                                                   unsigned* __restrict__ minenc, int N) {
    int lane = threadIdx.x & 63, w = threadIdx.x >> 6;
    int d = blockIdx.x * 4 + w;
    float out = INFINITY;
    if (d < N) {
        int row = rowptr[d], end = rowptr[d + 1];
        float sdv = sdst[d];
        float m = -INFINITY, l = 0.f, acc = 0.f;
        for (int base = row; base < end; base += 64) {
            int cnt = min(64, end - base);
            int sv = (lane < cnt) ? srcbuf[base + lane] : 0;
            for (int j = 0; j < cnt; j++) {
                int s = __shfl(sv, j, 64);
                float ss = ssrc[s];
                float hv = h2[(size_t)s * 64 + lane];
                float e = ss + sdv;
                e = e > 0.f ? e : 0.2f * e;
                float nm = fmaxf(m, e);
                float sc = __expf(m - nm);
                float wt = __expf(e - nm);
                acc = acc * sc + wt * hv;
                l = l * sc + wt;
                m = nm;
            }
        }
        out = acc / l + b2[lane];
    }
    __shared__ float sm[256];
    sm[threadIdx.x] = out;
    __syncthreads();
    if (w == 0) {
        float v = fminf(fminf(sm[lane], sm[64 + lane]), fminf(sm[128 + lane], sm[192 + lane]));
        atomicMin(&minenc[lane], fenc(v));
    }
}

__global__ void decode_kernel(const unsigned* __restrict__ minenc, float* __restrict__ out) {
    int d = threadIdx.x;
    if (d < 64) out[d] = fdec(minenc[d]);
}

// ---------- launch ----------
extern "C" void kernel_launch(void* const* d_in, const int* in_sizes, int n_in,
                              void* d_out, int out_size, void* d_ws, size_t ws_size,
                              hipStream_t stream) {
    const float* x      = (const float*)d_in[0];
    const int*   ei     = (const int*)d_in[1];
    const float* W1     = (const float*)d_in[2];
    const float* a_src1 = (const float*)d_in[3];
    const float* a_dst1 = (const float*)d_in[4];
    const float* b1     = (const float*)d_in[5];
    const float* W2     = (const float*)d_in[6];
    const float* a_src2 = (const float*)d_in[7];
    const float* a_dst2 = (const float*)d_in[8];
    const float* b2     = (const float*)d_in[9];
    float* out = (float*)d_out;

    const int N = in_sizes[0] / 128;
    const int E = in_sizes[1] / 2;
    const int Etot = E + N;
    const int M = N + 1;                      // scan extent (rowptr[N] = Etot)
    const int nchunks = (M + 255) / 256;      // must be <= 256 (N <= ~65k)

    // workspace layout (4-byte words)
    float* ws = (float*)d_ws;
    float* h1     = ws;                               // N*256
    float* x2     = h1 + (size_t)N * 256;             // N*256
    float* h2     = x2 + (size_t)N * 256;             // N*64
    float* ssrc1  = h2 + (size_t)N * 64;              // 4N (16B aligned)
    float* sdst1  = ssrc1 + (size_t)N * 4;            // 4N
    float* ssrc2  = sdst1 + (size_t)N * 4;            // N
    float* sdst2  = ssrc2 + N;                        // N
    int*   deg    = (int*)(sdst2 + N);                // N+1
    int*   rowptr = deg + M;                          // N+1
    int*   cursor = rowptr + M;                       // N
    int*   csum   = cursor + N;                       // 256
    int*   coff   = csum + 256;                       // 256
    int*   srcbuf = coff + 256;                       // Etot
    unsigned* minenc = (unsigned*)(srcbuf + Etot);    // 64

    hipMemsetAsync(deg, 0, (size_t)M * 4, stream);
    hipMemsetAsync(minenc, 0xFF, 64 * 4, stream);

    int nb16 = (N + 15) / 16;
    gemm1_kernel<<<nb16, 256, 0, stream>>>(x, W1, h1, N);
    scores1_kernel<<<N, 256, 0, stream>>>(h1, a_src1, a_dst1, ssrc1, sdst1, N);

    // CSR build (dst-grouped src indices)
    hist_kernel<<<(Etot + 255) / 256, 256, 0, stream>>>(ei, deg, E, Etot);
    chunksum_kernel<<<nchunks, 256, 0, stream>>>(deg, csum, M);
    scanchunks_kernel<<<1, 256, 0, stream>>>(csum, coff, nchunks);
    rowptr_kernel<<<nchunks, 256, 0, stream>>>(deg, coff, rowptr, M);
    hipMemcpyAsync(cursor, rowptr, (size_t)N * 4, hipMemcpyDeviceToDevice, stream);
    scatter_kernel<<<(Etot + 255) / 256, 256, 0, stream>>>(ei, cursor, srcbuf, E, Etot);

    agg1_kernel<<<(N + 3) / 4, 256, 0, stream>>>(rowptr, srcbuf, ssrc1, sdst1, h1, b1, x2, N);
    gemm2_kernel<<<nb16, 256, 0, stream>>>(x2, W2, h2, N);
    scores2_kernel<<<(N + 3) / 4, 256, 0, stream>>>(h2, a_src2, a_dst2, ssrc2, sdst2, N);
    agg2_kernel<<<(N + 3) / 4, 256, 0, stream>>>(rowptr, srcbuf, ssrc2, sdst2, h2, b2, minenc, N);
    decode_kernel<<<1, 64, 0, stream>>>(minenc, out);
}

// Round 3
// 630.955 us; speedup vs baseline: 2.4330x; 1.0292x over previous
//
#include <hip/hip_runtime.h>
#include <math.h>

// ---------- helpers ----------

__device__ inline unsigned fenc(float f) {
    unsigned u = __float_as_uint(f);
    return (u & 0x80000000u) ? ~u : (u | 0x80000000u);
}
__device__ inline float fdec(unsigned u) {
    return __uint_as_float((u & 0x80000000u) ? (u ^ 0x80000000u) : ~u);
}

__device__ inline float wrsum(float v) {
    #pragma unroll
    for (int m = 32; m; m >>= 1) v += __shfl_xor(v, m, 64);
    return v;
}
__device__ inline float wrmax(float v) {
    #pragma unroll
    for (int m = 32; m; m >>= 1) v = fmaxf(v, __shfl_xor(v, m, 64));
    return v;
}

// ---------- GEMM 1 + fused scores1.  h1p[n][dd][h] permuted layout ----------
__global__ __launch_bounds__(256) void gemm1_kernel(const float* __restrict__ x,
                                                    const float* __restrict__ W,
                                                    const float* __restrict__ a_src,
                                                    const float* __restrict__ a_dst,
                                                    float* __restrict__ h1p,
                                                    float* __restrict__ ssrc,
                                                    float* __restrict__ sdst, int N) {
    __shared__ float xs[16 * 128];
    int base = blockIdx.x * 16;
    int tid = threadIdx.x;
    const float4* xv = (const float4*)(x + (size_t)base * 128);
    float4* xsv = (float4*)xs;
    #pragma unroll
    for (int i = tid; i < 512; i += 256) {
        int n = base + (i >> 5);
        xsv[i] = (n < N) ? xv[i] : make_float4(0.f, 0.f, 0.f, 0.f);
    }
    __syncthreads();
    float acc[16];
    #pragma unroll
    for (int j = 0; j < 16; j++) acc[j] = 0.f;
    for (int k = 0; k < 128; k++) {
        float wk = W[k * 256 + tid];
        #pragma unroll
        for (int j = 0; j < 16; j++) acc[j] += xs[j * 128 + k] * wk;
    }
    int dd = tid & 63, hh = tid >> 6;
    #pragma unroll
    for (int j = 0; j < 16; j++) {
        int n = base + j;
        if (n < N) h1p[(size_t)n * 256 + dd * 4 + hh] = acc[j];
    }
    // fused scores: wave hh == head hh (a_src flat index == tid)
    float as = a_src[tid], ad = a_dst[tid];
    #pragma unroll
    for (int j = 0; j < 16; j++) {
        float ps = wrsum(acc[j] * as);
        float pd = wrsum(acc[j] * ad);
        int n = base + j;
        if (dd == 0 && n < N) {
            ssrc[n * 4 + hh] = ps;
            sdst[n * 4 + hh] = pd;
        }
    }
}

// ---------- GEMM 2 + fused scores2: h2[N,64] = x2[N,256] @ W2[256,64] ----------
__global__ __launch_bounds__(256) void gemm2_kernel(const float* __restrict__ x2,
                                                    const float* __restrict__ W,
                                                    const float* __restrict__ a_src,
                                                    const float* __restrict__ a_dst,
                                                    float* __restrict__ h2,
                                                    float* __restrict__ ssrc,
                                                    float* __restrict__ sdst, int N) {
    __shared__ float xs[16 * 256];
    int base = blockIdx.x * 16;
    int tid = threadIdx.x;
    const float4* xv = (const float4*)(x2 + (size_t)base * 256);
    float4* xsv = (float4*)xs;
    #pragma unroll
    for (int i = tid; i < 1024; i += 256) {
        int n = base + (i >> 6);
        xsv[i] = (n < N) ? xv[i] : make_float4(0.f, 0.f, 0.f, 0.f);
    }
    __syncthreads();
    int c = tid & 63, sub = tid >> 6;
    float acc[4] = {0.f, 0.f, 0.f, 0.f};
    for (int k = 0; k < 256; k++) {
        float wk = W[k * 64 + c];
        #pragma unroll
        for (int j = 0; j < 4; j++) acc[j] += xs[(sub + 4 * j) * 256 + k] * wk;
    }
    float as = a_src[c], ad = a_dst[c];
    #pragma unroll
    for (int j = 0; j < 4; j++) {
        int n = base + sub + 4 * j;
        if (n < N) h2[(size_t)n * 64 + c] = acc[j];
        float ps = wrsum(acc[j] * as);
        float pd = wrsum(acc[j] * ad);
        if (c == 0 && n < N) { ssrc[n] = ps; sdst[n] = pd; }
    }
}

// ---------- CSR build ----------
__global__ __launch_bounds__(256) void hist_kernel(const int* __restrict__ ei,
                                                   int* __restrict__ deg, int E, int Etot) {
    int i = blockIdx.x * 256 + threadIdx.x;
    if (i >= Etot) return;
    int d = (i < E) ? ei[E + i] : (i - E);
    atomicAdd(&deg[d], 1);
}

__global__ __launch_bounds__(256) void chunksum_kernel(const int* __restrict__ deg,
                                                       int* __restrict__ csum, int M) {
    __shared__ int sm[256];
    int t = blockIdx.x * 256 + threadIdx.x;
    sm[threadIdx.x] = (t < M) ? deg[t] : 0;
    __syncthreads();
    for (int off = 128; off > 0; off >>= 1) {
        if (threadIdx.x < off) sm[threadIdx.x] += sm[threadIdx.x + off];
        __syncthreads();
    }
    if (threadIdx.x == 0) csum[blockIdx.x] = sm[0];
}

__global__ __launch_bounds__(256) void scanchunks_kernel(const int* __restrict__ csum,
                                                         int* __restrict__ coffset, int nchunks) {
    __shared__ int sm[256];
    int v = (threadIdx.x < nchunks) ? csum[threadIdx.x] : 0;
    sm[threadIdx.x] = v;
    __syncthreads();
    for (int off = 1; off < 256; off <<= 1) {
        int a = (threadIdx.x >= off) ? sm[threadIdx.x - off] : 0;
        __syncthreads();
        sm[threadIdx.x] += a;
        __syncthreads();
    }
    coffset[threadIdx.x] = sm[threadIdx.x] - v;
}

__global__ __launch_bounds__(256) void rowptr_kernel(const int* __restrict__ deg,
                                                     const int* __restrict__ coffset,
                                                     int* __restrict__ rowptr,
                                                     int* __restrict__ cursor, int M, int N) {
    __shared__ int sm[256];
    int t = blockIdx.x * 256 + threadIdx.x;
    int v = (t < M) ? deg[t] : 0;
    sm[threadIdx.x] = v;
    __syncthreads();
    for (int off = 1; off < 256; off <<= 1) {
        int a = (threadIdx.x >= off) ? sm[threadIdx.x - off] : 0;
        __syncthreads();
        sm[threadIdx.x] += a;
        __syncthreads();
    }
    if (t < M) {
        int rp = coffset[blockIdx.x] + sm[threadIdx.x] - v;
        rowptr[t] = rp;
        if (t < N) cursor[t] = rp;
    }
}

__global__ __launch_bounds__(256) void scatter_kernel(const int* __restrict__ ei,
                                                      int* __restrict__ cursor,
                                                      int* __restrict__ srcbuf, int E, int Etot) {
    int i = blockIdx.x * 256 + threadIdx.x;
    if (i >= Etot) return;
    int s, d;
    if (i < E) { s = ei[i]; d = ei[E + i]; } else { s = d = i - E; }
    int pos = atomicAdd(&cursor[d], 1);
    srcbuf[pos] = s;
}

// ---------- layer-1 aggregation: wave/dst, lane-parallel weights + ILP gather ----------
__global__ __launch_bounds__(256) void agg1_kernel(const int* __restrict__ rowptr,
                                                   const int* __restrict__ srcbuf,
                                                   const float* __restrict__ ssrc,
                                                   const float* __restrict__ sdst,
                                                   const float* __restrict__ h1p,
                                                   const float* __restrict__ b1,
                                                   float* __restrict__ x2, int N) {
    __shared__ int    s_sh[4][64];
    __shared__ float4 w_sh[4][64];
    int lane = threadIdx.x & 63, w = threadIdx.x >> 6;
    int d = blockIdx.x * 4 + w;
    if (d >= N) return;
    int row = rowptr[d], end = rowptr[d + 1];
    float4 sd = *(const float4*)(sdst + d * 4);
    float m0 = -INFINITY, m1 = -INFINITY, m2 = -INFINITY, m3 = -INFINITY;
    float l0 = 0.f, l1 = 0.f, l2 = 0.f, l3 = 0.f;
    float a0 = 0.f, a1 = 0.f, a2 = 0.f, a3 = 0.f;

    for (int base = row; base < end; base += 64) {
        int cnt = min(64, end - base);
        bool valid = lane < cnt;
        int s = valid ? srcbuf[base + lane] : 0;
        float4 ss = *(const float4*)(ssrc + s * 4);
        float e0 = ss.x + sd.x, e1 = ss.y + sd.y, e2 = ss.z + sd.z, e3 = ss.w + sd.w;
        e0 = e0 > 0.f ? e0 : 0.2f * e0;  e1 = e1 > 0.f ? e1 : 0.2f * e1;
        e2 = e2 > 0.f ? e2 : 0.2f * e2;  e3 = e3 > 0.f ? e3 : 0.2f * e3;
        if (!valid) { e0 = e1 = e2 = e3 = -INFINITY; }
        float nm0 = fmaxf(m0, wrmax(e0)), nm1 = fmaxf(m1, wrmax(e1));
        float nm2 = fmaxf(m2, wrmax(e2)), nm3 = fmaxf(m3, wrmax(e3));
        float sc0 = __expf(m0 - nm0), sc1 = __expf(m1 - nm1);
        float sc2 = __expf(m2 - nm2), sc3 = __expf(m3 - nm3);
        float w0 = __expf(e0 - nm0), w1 = __expf(e1 - nm1);
        float w2 = __expf(e2 - nm2), w3 = __expf(e3 - nm3);
        l0 = l0 * sc0 + wrsum(w0);  l1 = l1 * sc1 + wrsum(w1);
        l2 = l2 * sc2 + wrsum(w2);  l3 = l3 * sc3 + wrsum(w3);
        a0 *= sc0; a1 *= sc1; a2 *= sc2; a3 *= sc3;
        m0 = nm0; m1 = nm1; m2 = nm2; m3 = nm3;
        s_sh[w][lane] = s;
        w_sh[w][lane] = make_float4(w0, w1, w2, w3);
        // wave-private LDS; lockstep wave, no barrier needed
        int cnt4 = (cnt + 3) & ~3;
        for (int j = 0; j < cnt4; j += 4) {
            int sj0 = s_sh[w][j], sj1 = s_sh[w][j + 1], sj2 = s_sh[w][j + 2], sj3 = s_sh[w][j + 3];
            float4 wj0 = w_sh[w][j], wj1 = w_sh[w][j + 1], wj2 = w_sh[w][j + 2], wj3 = w_sh[w][j + 3];
            float4 h0 = *(const float4*)(h1p + (size_t)sj0 * 256 + lane * 4);
            float4 h1 = *(const float4*)(h1p + (size_t)sj1 * 256 + lane * 4);
            float4 h2 = *(const float4*)(h1p + (size_t)sj2 * 256 + lane * 4);
            float4 h3 = *(const float4*)(h1p + (size_t)sj3 * 256 + lane * 4);
            a0 += wj0.x * h0.x; a1 += wj0.y * h0.y; a2 += wj0.z * h0.z; a3 += wj0.w * h0.w;
            a0 += wj1.x * h1.x; a1 += wj1.y * h1.y; a2 += wj1.z * h1.z; a3 += wj1.w * h1.w;
            a0 += wj2.x * h2.x; a1 += wj2.y * h2.y; a2 += wj2.z * h2.z; a3 += wj2.w * h2.w;
            a0 += wj3.x * h3.x; a1 += wj3.y * h3.y; a2 += wj3.z * h3.z; a3 += wj3.w * h3.w;
        }
    }
    float v0 = a0 / l0 + b1[lane];
    float v1 = a1 / l1 + b1[64 + lane];
    float v2 = a2 / l2 + b1[128 + lane];
    float v3 = a3 / l3 + b1[192 + lane];
    v0 = v0 > 0.f ? v0 : __expf(v0) - 1.f;
    v1 = v1 > 0.f ? v1 : __expf(v1) - 1.f;
    v2 = v2 > 0.f ? v2 : __expf(v2) - 1.f;
    v3 = v3 > 0.f ? v3 : __expf(v3) - 1.f;
    float* xp = x2 + (size_t)d * 256;
    xp[lane] = v0; xp[64 + lane] = v1; xp[128 + lane] = v2; xp[192 + lane] = v3;
}

// ---------- layer-2 aggregation + fused global min ----------
__global__ __launch_bounds__(256) void agg2_kernel(const int* __restrict__ rowptr,
                                                   const int* __restrict__ srcbuf,
                                                   const float* __restrict__ ssrc,
                                                   const float* __restrict__ sdst,
                                                   const float* __restrict__ h2,
                                                   const float* __restrict__ b2,
                                                   unsigned* __restrict__ minenc, int N) {
    __shared__ int   s_sh[4][64];
    __shared__ float w_sh[4][64];
    int lane = threadIdx.x & 63, w = threadIdx.x >> 6;
    int d = blockIdx.x * 4 + w;
    float out = INFINITY;
    if (d < N) {
        int row = rowptr[d], end = rowptr[d + 1];
        float sdv = sdst[d];
        float m = -INFINITY, l = 0.f;
        float a0 = 0.f, a1 = 0.f, a2 = 0.f, a3 = 0.f;
        for (int base = row; base < end; base += 64) {
            int cnt = min(64, end - base);
            bool valid = lane < cnt;
            int s = valid ? srcbuf[base + lane] : 0;
            float e = ssrc[s] + sdv;
            e = e > 0.f ? e : 0.2f * e;
            if (!valid) e = -INFINITY;
            float nm = fmaxf(m, wrmax(e));
            float sc = __expf(m - nm);
            float wt = __expf(e - nm);
            l = l * sc + wrsum(wt);
            a0 *= sc; a1 *= sc; a2 *= sc; a3 *= sc;
            m = nm;
            s_sh[w][lane] = s;
            w_sh[w][lane] = wt;
            int cnt8 = (cnt + 7) & ~7;
            for (int j = 0; j < cnt8; j += 8) {
                int   sj[8];
                float wj[8], hv[8];
                #pragma unroll
                for (int k = 0; k < 8; k++) { sj[k] = s_sh[w][j + k]; wj[k] = w_sh[w][j + k]; }
                #pragma unroll
                for (int k = 0; k < 8; k++) hv[k] = h2[(size_t)sj[k] * 64 + lane];
                a0 += wj[0] * hv[0]; a1 += wj[1] * hv[1]; a2 += wj[2] * hv[2]; a3 += wj[3] * hv[3];
                a0 += wj[4] * hv[4]; a1 += wj[5] * hv[5]; a2 += wj[6] * hv[6]; a3 += wj[7] * hv[7];
            }
        }
        out = ((a0 + a1) + (a2 + a3)) / l + b2[lane];
    }
    __shared__ float sm[256];
    sm[threadIdx.x] = out;
    __syncthreads();
    if (w == 0) {
        float v = fminf(fminf(sm[lane], sm[64 + lane]), fminf(sm[128 + lane], sm[192 + lane]));
        atomicMin(&minenc[lane], fenc(v));
    }
}

__global__ void decode_kernel(const unsigned* __restrict__ minenc, float* __restrict__ out) {
    int d = threadIdx.x;
    if (d < 64) out[d] = fdec(minenc[d]);
}

// ---------- launch ----------
extern "C" void kernel_launch(void* const* d_in, const int* in_sizes, int n_in,
                              void* d_out, int out_size, void* d_ws, size_t ws_size,
                              hipStream_t stream) {
    const float* x      = (const float*)d_in[0];
    const int*   ei     = (const int*)d_in[1];
    const float* W1     = (const float*)d_in[2];
    const float* a_src1 = (const float*)d_in[3];
    const float* a_dst1 = (const float*)d_in[4];
    const float* b1     = (const float*)d_in[5];
    const float* W2     = (const float*)d_in[6];
    const float* a_src2 = (const float*)d_in[7];
    const float* a_dst2 = (const float*)d_in[8];
    const float* b2     = (const float*)d_in[9];
    float* out = (float*)d_out;

    const int N = in_sizes[0] / 128;
    const int E = in_sizes[1] / 2;
    const int Etot = E + N;
    const int M = N + 1;
    const int nchunks = (M + 255) / 256;   // <= 256 for N <= ~65k

    float* ws = (float*)d_ws;
    float* h1p    = ws;                               // N*256 (permuted [n][dd][h])
    float* x2     = h1p + (size_t)N * 256;            // N*256
    float* h2     = x2 + (size_t)N * 256;             // N*64
    float* ssrc1  = h2 + (size_t)N * 64;              // 4N (16B aligned)
    float* sdst1  = ssrc1 + (size_t)N * 4;            // 4N
    float* ssrc2  = sdst1 + (size_t)N * 4;            // N
    float* sdst2  = ssrc2 + N;                        // N
    int*   deg    = (int*)(sdst2 + N);                // N+1
    int*   rowptr = deg + M;                          // N+1
    int*   cursor = rowptr + M;                       // N
    int*   csum   = cursor + N;                       // 256
    int*   coff   = csum + 256;                       // 256
    int*   srcbuf = coff + 256;                       // Etot
    unsigned* minenc = (unsigned*)(srcbuf + Etot);    // 64

    hipMemsetAsync(deg, 0, (size_t)M * 4, stream);
    hipMemsetAsync(minenc, 0xFF, 64 * 4, stream);

    int nb16 = (N + 15) / 16;
    gemm1_kernel<<<nb16, 256, 0, stream>>>(x, W1, a_src1, a_dst1, h1p, ssrc1, sdst1, N);

    hist_kernel<<<(Etot + 255) / 256, 256, 0, stream>>>(ei, deg, E, Etot);
    chunksum_kernel<<<nchunks, 256, 0, stream>>>(deg, csum, M);
    scanchunks_kernel<<<1, 256, 0, stream>>>(csum, coff, nchunks);
    rowptr_kernel<<<nchunks, 256, 0, stream>>>(deg, coff, rowptr, cursor, M, N);
    scatter_kernel<<<(Etot + 255) / 256, 256, 0, stream>>>(ei, cursor, srcbuf, E, Etot);

    agg1_kernel<<<(N + 3) / 4, 256, 0, stream>>>(rowptr, srcbuf, ssrc1, sdst1, h1p, b1, x2, N);
    gemm2_kernel<<<nb16, 256, 0, stream>>>(x2, W2, a_src2, a_dst2, h2, ssrc2, sdst2, N);
    agg2_kernel<<<(N + 3) / 4, 256, 0, stream>>>(rowptr, srcbuf, ssrc2, sdst2, h2, b2, minenc, N);
    decode_kernel<<<1, 64, 0, stream>>>(minenc, out);
}